// Round 2
// baseline (605.549 us; speedup 1.0000x reference)
//
#include <hip/hip_runtime.h>
#include <cstdint>
#include <cstddef>

typedef __attribute__((ext_vector_type(8))) short short8;
typedef __attribute__((ext_vector_type(4))) float f32x4;
typedef __attribute__((ext_vector_type(4))) short short4v;

__device__ __forceinline__ unsigned short f2bf(float f) {
  unsigned u = __builtin_bit_cast(unsigned, f);
  u += 0x7fffu + ((u >> 16) & 1u);   // round-to-nearest-even
  return (unsigned short)(u >> 16);
}

// Direct global->LDS DMA, 16 B per lane. LDS dest = wave-uniform base +
// lane*16 (linear); swizzle must be applied on the GLOBAL source address and
// again on the LDS read side (both-sides-or-neither).
__device__ __forceinline__ void gload_lds16(const unsigned short* g, unsigned short* l) {
  __builtin_amdgcn_global_load_lds(
      (__attribute__((address_space(1))) unsigned int*)g,
      (__attribute__((address_space(3))) unsigned int*)l, 16, 0, 0);
}

// ---------------- kernel 0: fp32 -> bf16 weight conversion (both weights) --
// grid (768, 2): y=0 -> w1 (786432 elems), y=1 -> w2. 768*256*4 = 786432 exact.
__global__ __launch_bounds__(256) void cvt_k(const float* __restrict__ w1,
                                             const float* __restrict__ w2,
                                             unsigned short* __restrict__ w1bf,
                                             unsigned short* __restrict__ w2bf) {
  const float* src = blockIdx.y ? w2 : w1;
  unsigned short* dst = blockIdx.y ? w2bf : w1bf;
  int i = (blockIdx.x * 256 + threadIdx.x) * 4;
  float4 v = *(const float4*)(src + i);
  short4v o;
  o.x = (short)f2bf(v.x); o.y = (short)f2bf(v.y);
  o.z = (short)f2bf(v.z); o.w = (short)f2bf(v.w);
  *(short4v*)(dst + i) = o;
}

// ---------------- fused kernel: stage1 + block-transpose + stage2 ----------
// Block = 32 batch rows. Phase 1: per kb (0..3), C1[32,192] = x-tile * w1[kb]^T
// accumulated over K=1024 (16 steps of 64), result written (block-transposed,
// bf16, XOR-swizzled) into LDS Yt[32][768]. Phase 2 (barrier-free): wave w
// owns l=w; A-frags (32x192 Yt slice) held in registers; w2 B-frags loaded
// DIRECT global->reg (each 4-lane cluster = one dense aligned 64B L2 line);
// 16 n-chunks of 64 cols; bias + scalar f32 stores (dense 64B segments).
// LDS 76 KB -> 2 blocks/CU; per-XCD L2 holds all weights (3 MB).
#define YT_SH (32 * 768)   // 24576 shorts = 48 KB
__global__ __launch_bounds__(256, 2) void fused_k(
    const float* __restrict__ x, const unsigned short* __restrict__ w1bf,
    const unsigned short* __restrict__ w2bf, const float* __restrict__ bias,
    float* __restrict__ out) {
  __shared__ __attribute__((aligned(16))) unsigned short sh[YT_SH + 2048 + 12288]; // 76 KB
  unsigned short* Yt = sh;                   // [32][768] swizzled bf16
  unsigned short* As = sh + YT_SH;           // [32][64]  swizzled bf16
  unsigned short* Bs = sh + YT_SH + 2048;    // [192][64] swizzled bf16

  const int t    = threadIdx.x;
  const int r0   = blockIdx.x * 32;
  const int lane = t & 63;
  const int w    = t >> 6;
  const int wm = w & 1, wn = w >> 1;
  const int lm = lane & 15, lk = lane >> 4;

  const int arow = t >> 3, ac8 = t & 7;      // x-stage mapping: 32 rows x 8 chunks
  const float* xrow = x + (size_t)(r0 + arow) * 4096 + ac8 * 8;
  const int ldsbase = (t & ~63) << 3;        // wave-uniform DMA dest base (shorts)

  // =============== phase 1: stage-1 GEMM into LDS Yt ===============
  // x prefetched one K-step ahead in registers (issue-early); post-MFMA
  // barrier is raw s_barrier + lgkmcnt(0) only, so the in-flight x prefetch
  // (vmcnt) survives the barrier and its HBM latency hides under compute.
  float4 px0 = *(const float4*)(xrow);
  float4 px1 = *(const float4*)(xrow + 4);

  for (int kb = 0; kb < 4; ++kb) {
    f32x4 acc[6];
#pragma unroll
    for (int j = 0; j < 6; ++j) acc[j] = (f32x4)0.0f;
    const unsigned short* wb = w1bf + (size_t)kb * 192 * 1024;

    for (int kt = 0; kt < 16; ++kt) {
      const int k0 = kt * 64;
      // ---- stage B: 192x64 bf16 via DMA, pre-swizzled source ----
#pragma unroll
      for (int i = 0; i < 6; ++i) {
        int c = i * 256 + t;               // chunk 0..1535 (16 B each)
        int row = c >> 3, slot = c & 7;
        gload_lds16(wb + (size_t)row * 1024 + k0 + ((slot ^ (row & 7)) << 3),
                    Bs + (i * 256 << 3) + ldsbase);
      }
      // ---- stage A: convert prefetched x regs -> swizzled ds_write ----
      short8 o;
      o[0] = (short)f2bf(px0.x); o[1] = (short)f2bf(px0.y);
      o[2] = (short)f2bf(px0.z); o[3] = (short)f2bf(px0.w);
      o[4] = (short)f2bf(px1.x); o[5] = (short)f2bf(px1.y);
      o[6] = (short)f2bf(px1.z); o[7] = (short)f2bf(px1.w);
      *(short8*)&As[(arow << 6) + ((ac8 ^ (arow & 7)) << 3)] = o;
      __syncthreads();   // drains DMA (vmcnt) + ds_write (lgkm); no x pending
      // ---- issue x prefetch for next K-step (flat index across kb) ----
      int nk = kb * 16 + kt + 1;
      if (nk < 64) {
        const float* p = xrow + (nk >> 4) * 1024 + (nk & 15) * 64;
        px0 = *(const float4*)p;
        px1 = *(const float4*)(p + 4);
      }
      // ---- MFMA: 2 k-steps of 32 ----
#pragma unroll
      for (int ks = 0; ks < 2; ++ks) {
        const int sl = ks * 4 + lk;
        const int ra = wm * 16 + lm;
        short8 a = *(const short8*)&As[(ra << 6) + ((sl ^ (ra & 7)) << 3)];
#pragma unroll
        for (int ct = 0; ct < 6; ++ct) {
          int rb = wn * 96 + ct * 16 + lm;
          short8 b = *(const short8*)&Bs[(rb << 6) + ((sl ^ (rb & 7)) << 3)];
          acc[ct] = __builtin_amdgcn_mfma_f32_16x16x32_bf16(a, b, acc[ct], 0, 0, 0);
        }
      }
      // raw barrier: only LDS reads must complete before restaging; keep the
      // x-prefetch (vmcnt) in flight across the barrier.
      asm volatile("s_waitcnt lgkmcnt(0)" ::: "memory");
      __builtin_amdgcn_s_barrier();
      __builtin_amdgcn_sched_barrier(0);
      asm volatile("" ::: "memory");
    }
    // ---- kb epilogue: acc -> Yt (LDS, block-transposed, swizzled) ----
#pragma unroll
    for (int ct = 0; ct < 6; ++ct) {
      int q  = wn * 96 + ct * 16 + lm;       // 0..191 within kb
      int li = q / 48, j = q - li * 48;
      int ycol  = li * 192 + kb * 48 + j;    // col in [0,768)
      int yslot = ycol >> 3, yoff = ycol & 7;
#pragma unroll
      for (int reg = 0; reg < 4; ++reg) {
        int row = wm * 16 + lk * 4 + reg;
        Yt[row * 768 + ((yslot ^ (row & 7)) << 3) + yoff] = f2bf(acc[ct][reg]);
      }
    }
  }

  __syncthreads();   // all Yt writes visible; last barrier in the kernel

  // =============== phase 2: stage-2 GEMM, barrier-free ===============
  const int l = w;                               // wave w owns l-slice w
  const unsigned short* w2b = w2bf + (size_t)l * 1024 * 192;

  // A fragments: 32x192 Yt slice, held in registers for all 16 n-chunks
  short8 af[2][6];
#pragma unroll
  for (int rt = 0; rt < 2; ++rt)
#pragma unroll
    for (int ks = 0; ks < 6; ++ks) {
      int row  = rt * 16 + lm;
      int slot = l * 24 + ks * 4 + lk;
      af[rt][ks] = *(const short8*)&Yt[row * 768 + ((slot ^ (row & 7)) << 3)];
    }

  for (int nc = 0; nc < 16; ++nc) {
    const int n0 = nc * 64;
    f32x4 acc[2][4];
#pragma unroll
    for (int rt = 0; rt < 2; ++rt)
#pragma unroll
      for (int ct = 0; ct < 4; ++ct) acc[rt][ct] = (f32x4)0.0f;

#pragma unroll
    for (int ks = 0; ks < 6; ++ks) {
      short8 b[4];
#pragma unroll
      for (int ct = 0; ct < 4; ++ct)
        b[ct] = *(const short8*)(w2b + (size_t)(n0 + ct * 16 + lm) * 192 + ks * 32 + lk * 8);
#pragma unroll
      for (int rt = 0; rt < 2; ++rt)
#pragma unroll
        for (int ct = 0; ct < 4; ++ct)
          acc[rt][ct] = __builtin_amdgcn_mfma_f32_16x16x32_bf16(af[rt][ks], b[ct], acc[rt][ct], 0, 0, 0);
    }

    float bv[4];
#pragma unroll
    for (int ct = 0; ct < 4; ++ct)
      bv[ct] = bias[l * 1024 + n0 + ct * 16 + lm];
#pragma unroll
    for (int rt = 0; rt < 2; ++rt)
#pragma unroll
      for (int ct = 0; ct < 4; ++ct)
#pragma unroll
        for (int reg = 0; reg < 4; ++reg)
          out[(size_t)(r0 + rt * 16 + lk * 4 + reg) * 4096 + l * 1024 + n0 + ct * 16 + lm] =
              acc[rt][ct][reg] + bv[ct];
  }
}

// ---------------- launch ---------------------------------------------------
extern "C" void kernel_launch(void* const* d_in, const int* in_sizes, int n_in,
                              void* d_out, int out_size, void* d_ws, size_t ws_size,
                              hipStream_t stream) {
  const float* x    = (const float*)d_in[0];
  const float* w1   = (const float*)d_in[1];
  const float* w2   = (const float*)d_in[2];
  const float* bias = (const float*)d_in[3];
  float* out = (float*)d_out;

  // workspace: w1bf (1.5 MB) | w2bf (1.5 MB). Y intermediate eliminated.
  unsigned short* w1bf = (unsigned short*)d_ws;
  unsigned short* w2bf = (unsigned short*)((char*)d_ws + 1572864);

  cvt_k<<<dim3(768, 2), 256, 0, stream>>>(w1, w2, w1bf, w2bf);
  fused_k<<<512, 256, 0, stream>>>(x, w1bf, w2bf, bias, out);
}